// Round 1
// baseline (71.843 us; speedup 1.0000x reference)
//
#include <hip/hip_runtime.h>

// PatchConsistencyLoss: structure [32,32,32,32] int32, patch 4x4x4.
// Per patch (one wave = 64 lanes = 64 voxels):
//   histogram over <=64 values via lane-broadcast counting,
//   drop air tokens {102,576,3352}, entropy = -sum p*log(p+1e-10),
//   p = count/max(tot,1). Sum over 16384 patches / (16384 + 1e-6).

__global__ __launch_bounds__(256) void pcl_k1(const int* __restrict__ s,
                                              float* __restrict__ partial) {
    const int lane = threadIdx.x & 63;
    const int wave = threadIdx.x >> 6;
    const int patch = (blockIdx.x << 2) + wave;   // 4096 blocks * 4 waves = 16384

    // patch = ((b*8 + pd)*8 + ph)*8 + pw   (order irrelevant; grouping matters)
    const int b  = patch >> 9;
    const int pd = (patch >> 6) & 7;
    const int ph = (patch >> 3) & 7;
    const int pw = patch & 7;

    // lane -> (ld, lh, lw) in [0,4)^3
    const int ld = lane >> 4;
    const int lh = (lane >> 2) & 3;
    const int lw = lane & 3;

    const int d = (pd << 2) + ld;
    const int h = (ph << 2) + lh;
    const int w = (pw << 2) + lw;
    const int idx = ((b * 32 + d) * 32 + h) * 32 + w;

    const int tok = s[idx];
    const bool air = (tok == 102) | (tok == 576) | (tok == 3352);

    // total non-air tokens in this patch
    const unsigned long long nb = __ballot(!air);
    const int tot = __popcll(nb);

    // per-lane: count of lanes with my token, and first lane holding it
    int cnt = 0;
    int first = -1;
#pragma unroll
    for (int j = 0; j < 64; ++j) {
        const int t = __shfl(tok, j, 64);   // constant src lane -> v_readlane
        if (t == tok) {
            ++cnt;
            if (first < 0) first = j;
        }
    }

    float e = 0.0f;
    if (!air && first == lane) {            // representative lane for this token
        const float p = (float)cnt / (float)tot;   // tot >= 1 here
        e = -p * __logf(p + 1e-10f);
    }

    // wave reduction
#pragma unroll
    for (int off = 32; off > 0; off >>= 1) e += __shfl_xor(e, off, 64);

    __shared__ float ws4[4];
    if (lane == 0) ws4[wave] = e;
    __syncthreads();
    if (threadIdx.x == 0)
        partial[blockIdx.x] = ws4[0] + ws4[1] + ws4[2] + ws4[3];
}

__global__ __launch_bounds__(256) void pcl_k2(const float* __restrict__ partial,
                                              float* __restrict__ out, int n) {
    float sum = 0.0f;
    for (int i = threadIdx.x; i < n; i += 256) sum += partial[i];
#pragma unroll
    for (int off = 32; off > 0; off >>= 1) sum += __shfl_xor(sum, off, 64);

    __shared__ float ws4[4];
    const int lane = threadIdx.x & 63;
    const int wave = threadIdx.x >> 6;
    if (lane == 0) ws4[wave] = sum;
    __syncthreads();
    if (threadIdx.x == 0) {
        const float t = ws4[0] + ws4[1] + ws4[2] + ws4[3];
        out[0] = t * (1.0f / (16384.0f + 1e-6f));
    }
}

extern "C" void kernel_launch(void* const* d_in, const int* in_sizes, int n_in,
                              void* d_out, int out_size, void* d_ws, size_t ws_size,
                              hipStream_t stream) {
    const int* s = (const int*)d_in[0];
    float* out = (float*)d_out;
    float* partial = (float*)d_ws;   // 4096 floats = 16 KB scratch

    pcl_k1<<<4096, 256, 0, stream>>>(s, partial);
    pcl_k2<<<1, 256, 0, stream>>>(partial, out, 4096);
}

// Round 2
// 59.825 us; speedup vs baseline: 1.2009x; 1.2009x over previous
//
#include <hip/hip_runtime.h>

// PatchConsistencyLoss: structure [32,32,32,32] int32, patch 4x4x4 (64 voxels
// = one wave). Per-patch token histogram via 12-ballot bitwise match-mask
// (VOCAB=3717 < 4096): lanes with equal tokens get identical 64-bit masks.
// Representative lane (first in mask, non-air) contributes -p*log(p+1e-10),
// p = count/tot(non-air). Air = {102, 576, 3352}. Sum / (16384 + 1e-6).
//
// Each wave processes 4 patches (amortize reduce+write): 1024 blocks x 256.

__global__ __launch_bounds__(256) void pcl_k1(const int* __restrict__ s,
                                              float* __restrict__ partial) {
    const int lane = threadIdx.x & 63;
    const int wave = threadIdx.x >> 6;
    const int wid = (blockIdx.x << 2) + wave;   // 0..4095, 4 patches each

    // lane -> (ld, lh, lw) within the 4x4x4 patch
    const int ld = lane >> 4;
    const int lh = (lane >> 2) & 3;
    const int lw = lane & 3;

    float e = 0.0f;
#pragma unroll
    for (int it = 0; it < 4; ++it) {
        const int patch = (wid << 2) + it;      // 0..16383
        // patch = ((b*8 + pd)*8 + ph)*8 + pw
        const int b  = patch >> 9;
        const int pd = (patch >> 6) & 7;
        const int ph = (patch >> 3) & 7;
        const int pw = patch & 7;
        const int idx = ((b * 32 + (pd << 2) + ld) * 32 + (ph << 2) + lh) * 32
                        + (pw << 2) + lw;

        const int tok = s[idx];
        const bool air = (tok == 102) || (tok == 576) || (tok == 3352);
        const int tot = __popcll(__ballot(!air));

        // bitwise match-mask: lanes holding my exact token value
        unsigned long long m = ~0ull;
#pragma unroll
        for (int bit = 0; bit < 12; ++bit) {
            const unsigned long long bal = __ballot((tok >> bit) & 1);
            m &= ((tok >> bit) & 1) ? bal : ~bal;
        }

        const int first = __ffsll((unsigned long long)m) - 1;
        if (!air && first == lane) {            // one representative per token
            const float p = (float)__popcll(m) / (float)tot;  // tot >= 1 here
            e -= p * __logf(p + 1e-10f);
        }
    }

    // wave reduction
#pragma unroll
    for (int off = 32; off > 0; off >>= 1) e += __shfl_xor(e, off, 64);

    __shared__ float ws4[4];
    if (lane == 0) ws4[wave] = e;
    __syncthreads();
    if (threadIdx.x == 0)
        partial[blockIdx.x] = ws4[0] + ws4[1] + ws4[2] + ws4[3];
}

__global__ __launch_bounds__(256) void pcl_k2(const float* __restrict__ partial,
                                              float* __restrict__ out, int n) {
    float sum = 0.0f;
    for (int i = threadIdx.x; i < n; i += 256) sum += partial[i];
#pragma unroll
    for (int off = 32; off > 0; off >>= 1) sum += __shfl_xor(sum, off, 64);

    __shared__ float ws4[4];
    const int lane = threadIdx.x & 63;
    const int wave = threadIdx.x >> 6;
    if (lane == 0) ws4[wave] = sum;
    __syncthreads();
    if (threadIdx.x == 0) {
        const float t = ws4[0] + ws4[1] + ws4[2] + ws4[3];
        out[0] = t * (1.0f / (16384.0f + 1e-6f));
    }
}

extern "C" void kernel_launch(void* const* d_in, const int* in_sizes, int n_in,
                              void* d_out, int out_size, void* d_ws, size_t ws_size,
                              hipStream_t stream) {
    const int* s = (const int*)d_in[0];
    float* out = (float*)d_out;
    float* partial = (float*)d_ws;   // 1024 floats = 4 KB scratch

    pcl_k1<<<1024, 256, 0, stream>>>(s, partial);
    pcl_k2<<<1, 256, 0, stream>>>(partial, out, 1024);
}